// Round 11
// baseline (19.489 us; speedup 1.0000x reference)
//
#include <hip/hip_runtime.h>

constexpr int N = 512;
constexpr int D = 128;
constexpr int A = 2;             // anchors per block
constexpr int NBLK = N / A;      // 256 blocks = 1 per CU
constexpr float MARGIN = 1.0f;
constexpr float EPS_T = 1e-16f;

// Main: 2 anchors/block, 256 blocks, 512 threads. Stream-fused: the 512-row
// sweep computes distances in-register and hinges them immediately — no drow
// LDS round-trip, no barrier inside the sweep.
//  S0: stage labels; ballot-compact positive INDEX lists (both anchors).
//  S1: compute the ~32 positive distances -> posd (one small pass). Barrier.
//  S2: 8 barrier-free passes over all rows; 8 lanes/row (sub = tid&7) read
//      float4 chunks {sub,sub+8,sub+16,sub+24} (coalesced); diff-FMA + 8-lane
//      shfl_xor tree (bitwise-identical distances to R9); hinge vs posd
//      immediately, each lane covering q = sub, sub+8, ... of the positives.
//  S3: fixed-tree f64 reduction -> partial[4*blk + {0,1,2}].
// Final: ONE WAVE, no LDS: grid partials -> two scalars.
__global__ __launch_bounds__(512, 2) void triplet_main_k(
    const float* __restrict__ emb, const int* __restrict__ labels,
    double* __restrict__ partial)
{
    __shared__ int    lab[N];
    __shared__ int    plist[2 * 64];   // [0..63] anchor0 rows, [64..127] anchor1
    __shared__ float  posd[2][64];
    __shared__ int    cnt[2][8];
    __shared__ int    npos_s[2];
    __shared__ double red[24];         // [0..7]=sum, [8..15]=npos, [16..23]=ntrip

    const int i0   = blockIdx.x * A;
    const int tid  = threadIdx.x;
    const int lane = tid & 63;
    const int wid  = tid >> 6;
    const int sub  = tid & 7;
    const int grp  = tid >> 3;         // 64 row-groups of 8 lanes

    // anchors -> registers (8-lane broadcast loads)
    const float4* ea0 = reinterpret_cast<const float4*>(emb + (size_t)i0 * D);
    const float4* ea1 = reinterpret_cast<const float4*>(emb + (size_t)(i0 + 1) * D);
    const float4 a00 = ea0[sub], a01 = ea0[sub + 8], a02 = ea0[sub + 16], a03 = ea0[sub + 24];
    const float4 a10 = ea1[sub], a11 = ea1[sub + 8], a12 = ea1[sub + 16], a13 = ea1[sub + 24];

    lab[tid] = labels[tid];
    const int li0 = labels[i0];
    const int li1 = labels[i0 + 1];
    __syncthreads();

    // ---- S0: compact positive index lists (ascending-j, deterministic) ----
    const int j = tid;
    const bool p0 = (lab[j] == li0) && (j != i0);
    const bool p1 = (lab[j] == li1) && (j != i0 + 1);
    const unsigned long long m0 = __ballot(p0);
    const unsigned long long m1 = __ballot(p1);
    if (lane == 0) { cnt[0][wid] = __popcll(m0); cnt[1][wid] = __popcll(m1); }
    __syncthreads();
    int base0 = 0, base1 = 0;
    #pragma unroll
    for (int w = 0; w < 8; ++w) {
        base0 += (w < wid) ? cnt[0][w] : 0;
        base1 += (w < wid) ? cnt[1][w] : 0;
    }
    const unsigned long long lm = (1ull << lane) - 1ull;
    if (p0) plist[base0 + __popcll(m0 & lm)]      = j;
    if (p1) plist[64 + base1 + __popcll(m1 & lm)] = j;
    if (tid == 0) {
        int t0 = 0, t1 = 0;
        #pragma unroll
        for (int w = 0; w < 8; ++w) { t0 += cnt[0][w]; t1 += cnt[1][w]; }
        npos_s[0] = t0; npos_s[1] = t1;
    }
    __syncthreads();

    const int np0 = npos_s[0];
    const int np1 = npos_s[1];

    // ---- S1: positive distances -> posd ----
    for (int e = grp; e < np0 + np1; e += 64) {
        const int  a   = (e < np0) ? 0 : 1;
        const int  idx = (e < np0) ? e : (e - np0);
        const int  row = plist[a * 64 + idx];
        const float4* er = reinterpret_cast<const float4*>(emb + (size_t)row * D);
        const float4 v0 = er[sub], v1 = er[sub + 8], v2 = er[sub + 16], v3 = er[sub + 24];
        float sq0 = 0.f, sq1 = 0.f;
        {
            float d0 = a00.x - v0.x, d1 = a00.y - v0.y, d2 = a00.z - v0.z, d3 = a00.w - v0.w;
            sq0 += d0 * d0 + d1 * d1 + d2 * d2 + d3 * d3;
            d0 = a01.x - v1.x; d1 = a01.y - v1.y; d2 = a01.z - v1.z; d3 = a01.w - v1.w;
            sq0 += d0 * d0 + d1 * d1 + d2 * d2 + d3 * d3;
            d0 = a02.x - v2.x; d1 = a02.y - v2.y; d2 = a02.z - v2.z; d3 = a02.w - v2.w;
            sq0 += d0 * d0 + d1 * d1 + d2 * d2 + d3 * d3;
            d0 = a03.x - v3.x; d1 = a03.y - v3.y; d2 = a03.z - v3.z; d3 = a03.w - v3.w;
            sq0 += d0 * d0 + d1 * d1 + d2 * d2 + d3 * d3;
        }
        {
            float d0 = a10.x - v0.x, d1 = a10.y - v0.y, d2 = a10.z - v0.z, d3 = a10.w - v0.w;
            sq1 += d0 * d0 + d1 * d1 + d2 * d2 + d3 * d3;
            d0 = a11.x - v1.x; d1 = a11.y - v1.y; d2 = a11.z - v1.z; d3 = a11.w - v1.w;
            sq1 += d0 * d0 + d1 * d1 + d2 * d2 + d3 * d3;
            d0 = a12.x - v2.x; d1 = a12.y - v2.y; d2 = a12.z - v2.z; d3 = a12.w - v2.w;
            sq1 += d0 * d0 + d1 * d1 + d2 * d2 + d3 * d3;
            d0 = a13.x - v3.x; d1 = a13.y - v3.y; d2 = a13.z - v3.z; d3 = a13.w - v3.w;
            sq1 += d0 * d0 + d1 * d1 + d2 * d2 + d3 * d3;
        }
        sq0 += __shfl_xor(sq0, 1); sq1 += __shfl_xor(sq1, 1);
        sq0 += __shfl_xor(sq0, 2); sq1 += __shfl_xor(sq1, 2);
        sq0 += __shfl_xor(sq0, 4); sq1 += __shfl_xor(sq1, 4);
        const float sq = (e < np0) ? sq0 : sq1;
        if (sub == 0) posd[a][idx] = (sq > 0.f) ? sqrtf(sq) : 0.f;   // safe sqrt
    }
    __syncthreads();

    // ---- S2: barrier-free streaming sweep with fused hinge ----
    double sum = 0.0;
    int np_i = 0, nt_i = 0;
    #pragma unroll 2
    for (int p = 0; p < 8; ++p) {
        const int r = p * 64 + grp;
        const float4* er = reinterpret_cast<const float4*>(emb + (size_t)r * D);
        const float4 v0 = er[sub], v1 = er[sub + 8], v2 = er[sub + 16], v3 = er[sub + 24];
        float sq0 = 0.f, sq1 = 0.f;
        {
            float d0 = a00.x - v0.x, d1 = a00.y - v0.y, d2 = a00.z - v0.z, d3 = a00.w - v0.w;
            sq0 += d0 * d0 + d1 * d1 + d2 * d2 + d3 * d3;
            d0 = a01.x - v1.x; d1 = a01.y - v1.y; d2 = a01.z - v1.z; d3 = a01.w - v1.w;
            sq0 += d0 * d0 + d1 * d1 + d2 * d2 + d3 * d3;
            d0 = a02.x - v2.x; d1 = a02.y - v2.y; d2 = a02.z - v2.z; d3 = a02.w - v2.w;
            sq0 += d0 * d0 + d1 * d1 + d2 * d2 + d3 * d3;
            d0 = a03.x - v3.x; d1 = a03.y - v3.y; d2 = a03.z - v3.z; d3 = a03.w - v3.w;
            sq0 += d0 * d0 + d1 * d1 + d2 * d2 + d3 * d3;
        }
        {
            float d0 = a10.x - v0.x, d1 = a10.y - v0.y, d2 = a10.z - v0.z, d3 = a10.w - v0.w;
            sq1 += d0 * d0 + d1 * d1 + d2 * d2 + d3 * d3;
            d0 = a11.x - v1.x; d1 = a11.y - v1.y; d2 = a11.z - v1.z; d3 = a11.w - v1.w;
            sq1 += d0 * d0 + d1 * d1 + d2 * d2 + d3 * d3;
            d0 = a12.x - v2.x; d1 = a12.y - v2.y; d2 = a12.z - v2.z; d3 = a12.w - v2.w;
            sq1 += d0 * d0 + d1 * d1 + d2 * d2 + d3 * d3;
            d0 = a13.x - v3.x; d1 = a13.y - v3.y; d2 = a13.z - v3.z; d3 = a13.w - v3.w;
            sq1 += d0 * d0 + d1 * d1 + d2 * d2 + d3 * d3;
        }
        sq0 += __shfl_xor(sq0, 1); sq1 += __shfl_xor(sq1, 1);
        sq0 += __shfl_xor(sq0, 2); sq1 += __shfl_xor(sq1, 2);
        sq0 += __shfl_xor(sq0, 4); sq1 += __shfl_xor(sq1, 4);
        const float dk0 = (sq0 > 0.f) ? sqrtf(sq0) : 0.f;   // safe sqrt
        const float dk1 = (sq1 > 0.f) ? sqrtf(sq1) : 0.f;
        const int   lr  = lab[r];                            // row-uniform per group
        if (lr != li0) {                                     // r is a negative for a0
            for (int q = sub; q < np0; q += 8) {
                const float t = (posd[0][q] - dk0) + MARGIN; // reference op order
                ++nt_i;
                if (t > EPS_T) { sum += (double)t; ++np_i; }
            }
        }
        if (lr != li1) {                                     // r is a negative for a1
            for (int q = sub; q < np1; q += 8) {
                const float t = (posd[1][q] - dk1) + MARGIN;
                ++nt_i;
                if (t > EPS_T) { sum += (double)t; ++np_i; }
            }
        }
    }

    // ---- S3: fixed-tree reduction ----
    double s = sum, p = (double)np_i, t = (double)nt_i;
    #pragma unroll
    for (int off = 32; off > 0; off >>= 1) {
        s += __shfl_down(s, off);
        p += __shfl_down(p, off);
        t += __shfl_down(t, off);
    }
    if (lane == 0) { red[wid] = s; red[8 + wid] = p; red[16 + wid] = t; }
    __syncthreads();
    if (tid == 0) {
        double S = 0.0, P = 0.0, T = 0.0;
        #pragma unroll
        for (int w = 0; w < 8; ++w) { S += red[w]; P += red[8 + w]; T += red[16 + w]; }
        partial[4 * blockIdx.x + 0] = S;
        partial[4 * blockIdx.x + 1] = P;
        partial[4 * blockIdx.x + 2] = T;
    }
}

// Single-wave finalizer: no LDS, no barrier.
__global__ __launch_bounds__(64) void triplet_final_k(
    const double* __restrict__ partial, float* __restrict__ out)
{
    const int lane = threadIdx.x;
    double a = 0.0, b = 0.0, c = 0.0;
    #pragma unroll
    for (int bk = lane; bk < NBLK; bk += 64) {
        a += partial[4 * bk + 0];
        b += partial[4 * bk + 1];
        c += partial[4 * bk + 2];
    }
    #pragma unroll
    for (int off = 32; off > 0; off >>= 1) {
        a += __shfl_down(a, off);
        b += __shfl_down(b, off);
        c += __shfl_down(c, off);
    }
    if (lane == 0) {
        out[0] = (float)(a / (b + 1e-16));  // loss
        out[1] = (float)(b / (c + 1e-16));  // fraction_positive
    }
}

extern "C" void kernel_launch(void* const* d_in, const int* in_sizes, int n_in,
                              void* d_out, int out_size, void* d_ws, size_t ws_size,
                              hipStream_t stream) {
    const float* emb   = (const float*)d_in[0];   // [512,128] f32
    const int*   lab   = (const int*)d_in[1];     // [512] i32
    float*       out   = (float*)d_out;           // [2] f32: loss, fraction_positive
    double*      parts = (double*)d_ws;           // 4*NBLK doubles = 8 KB

    triplet_main_k<<<NBLK, 512, 0, stream>>>(emb, lab, parts);
    triplet_final_k<<<1, 64, 0, stream>>>(parts, out);
}

// Round 12
// 14.924 us; speedup vs baseline: 1.3059x; 1.3059x over previous
//
#include <hip/hip_runtime.h>

constexpr int N = 512;
constexpr int D = 128;
constexpr int A = 2;             // anchors per block
constexpr int NBLK = N / A;      // 256 blocks = 1 per CU
constexpr float MARGIN = 1.0f;
constexpr float EPS_T = 1e-16f;

// Main: 2 anchors/block, 256 blocks, 512 threads.
//  P1: 4 passes, 4 lanes/row (HALF the passes of R9 -> half the serial chain;
//      latency-bound regime measured R9/R10/R11: chain length is what pays).
//      Lane sub4 = tid&3 reads float4 chunks {sub4, sub4+4, ..., sub4+28}:
//      4 lanes cover a row's 64-B windows (50% line util; traffic elasticity
//      measured weak). Tree depth 2 (xor 1,2) -> drow.
//  P2: all 8 waves ballot-compact both anchors' positive distances (ascending
//      j preserved -> deterministic).
//  P3: thread's k (= tid) hinges vs both anchors' positives (~32 iters).
//  P4: fixed-tree f64 reduction -> partial[4*blk + {0,1,2}].
// Final: single wave, no LDS, no barrier.
__global__ __launch_bounds__(512) void triplet_main_k(
    const float* __restrict__ emb, const int* __restrict__ labels,
    double* __restrict__ partial)
{
    __shared__ float  drow[A][N];
    __shared__ float  posd[A][128];
    __shared__ int    cnt[A][8];
    __shared__ int    npos_s[A];
    __shared__ double red[24];   // [0..7]=sum, [8..15]=npos, [16..23]=ntrip

    const int i0   = blockIdx.x * A;
    const int tid  = threadIdx.x;
    const int lane = tid & 63;
    const int wid  = tid >> 6;
    const int sub4 = tid & 3;

    // anchors -> registers: 8 chunks per anchor (4-lane broadcast loads)
    const float4* ea0 = reinterpret_cast<const float4*>(emb + (size_t)i0 * D);
    const float4* ea1 = reinterpret_cast<const float4*>(emb + (size_t)(i0 + 1) * D);
    float4 A0[8], A1[8];
    #pragma unroll
    for (int c = 0; c < 8; ++c) { A0[c] = ea0[sub4 + 4 * c]; A1[c] = ea1[sub4 + 4 * c]; }

    const int lk  = labels[tid];        // this thread's k-label
    const int li0 = labels[i0];         // uniform broadcasts
    const int li1 = labels[i0 + 1];

    // ---- P1: 4 passes, 4 lanes/row, both anchors ----
    #pragma unroll 2
    for (int p = 0; p < 4; ++p) {
        const int r = p * 128 + (tid >> 2);
        const float4* er = reinterpret_cast<const float4*>(emb + (size_t)r * D);
        float4 V[8];
        #pragma unroll
        for (int c = 0; c < 8; ++c) V[c] = er[sub4 + 4 * c];
        float sq0 = 0.f, sq1 = 0.f;
        #pragma unroll
        for (int c = 0; c < 8; ++c) {
            float d0 = A0[c].x - V[c].x, d1 = A0[c].y - V[c].y;
            float d2 = A0[c].z - V[c].z, d3 = A0[c].w - V[c].w;
            sq0 += d0 * d0 + d1 * d1 + d2 * d2 + d3 * d3;
            d0 = A1[c].x - V[c].x; d1 = A1[c].y - V[c].y;
            d2 = A1[c].z - V[c].z; d3 = A1[c].w - V[c].w;
            sq1 += d0 * d0 + d1 * d1 + d2 * d2 + d3 * d3;
        }
        sq0 += __shfl_xor(sq0, 1); sq1 += __shfl_xor(sq1, 1);
        sq0 += __shfl_xor(sq0, 2); sq1 += __shfl_xor(sq1, 2);
        if (sub4 == 0) {
            drow[0][r] = (sq0 > 0.f) ? sqrtf(sq0) : 0.f;   // safe sqrt
            drow[1][r] = (sq1 > 0.f) ? sqrtf(sq1) : 0.f;
        }
    }
    __syncthreads();

    // ---- P2: parallel compaction, all 8 waves (ascending-j order kept) ----
    const int j = tid;
    const bool p0 = (labels[j] == li0) && (j != i0);
    const bool p1 = (labels[j] == li1) && (j != i0 + 1);
    const unsigned long long m0 = __ballot(p0);
    const unsigned long long m1 = __ballot(p1);
    if (lane == 0) { cnt[0][wid] = __popcll(m0); cnt[1][wid] = __popcll(m1); }
    __syncthreads();
    int base0 = 0, base1 = 0;
    #pragma unroll
    for (int w = 0; w < 8; ++w) {
        base0 += (w < wid) ? cnt[0][w] : 0;
        base1 += (w < wid) ? cnt[1][w] : 0;
    }
    const unsigned long long lm = (1ull << lane) - 1ull;
    if (p0) posd[0][base0 + __popcll(m0 & lm)] = drow[0][j];
    if (p1) posd[1][base1 + __popcll(m1 & lm)] = drow[1][j];
    if (tid == 0) {
        int t0 = 0, t1 = 0;
        #pragma unroll
        for (int w = 0; w < 8; ++w) { t0 += cnt[0][w]; t1 += cnt[1][w]; }
        npos_s[0] = t0; npos_s[1] = t1;
    }
    __syncthreads();

    // ---- P3: hinge accumulation, k = tid, both anchors ----
    double sum = 0.0;
    int np_i = 0, nt_i = 0;
    {
        const float dik = drow[0][tid];
        if (lk != li0) {
            const int npos = npos_s[0];
            for (int p = 0; p < npos; ++p) {
                const float t = (posd[0][p] - dik) + MARGIN;  // reference op order
                if (t > EPS_T) { sum += (double)t; ++np_i; }
            }
            nt_i += npos;
        }
    }
    {
        const float dik = drow[1][tid];
        if (lk != li1) {
            const int npos = npos_s[1];
            for (int p = 0; p < npos; ++p) {
                const float t = (posd[1][p] - dik) + MARGIN;
                if (t > EPS_T) { sum += (double)t; ++np_i; }
            }
            nt_i += npos;
        }
    }

    // ---- P4: fixed-tree reduction ----
    double s = sum, p = (double)np_i, t = (double)nt_i;
    #pragma unroll
    for (int off = 32; off > 0; off >>= 1) {
        s += __shfl_down(s, off);
        p += __shfl_down(p, off);
        t += __shfl_down(t, off);
    }
    if (lane == 0) { red[wid] = s; red[8 + wid] = p; red[16 + wid] = t; }
    __syncthreads();
    if (tid == 0) {
        double S = 0.0, P = 0.0, T = 0.0;
        #pragma unroll
        for (int w = 0; w < 8; ++w) { S += red[w]; P += red[8 + w]; T += red[16 + w]; }
        partial[4 * blockIdx.x + 0] = S;
        partial[4 * blockIdx.x + 1] = P;
        partial[4 * blockIdx.x + 2] = T;
    }
}

// Single-wave finalizer: no LDS, no barrier.
__global__ __launch_bounds__(64) void triplet_final_k(
    const double* __restrict__ partial, float* __restrict__ out)
{
    const int lane = threadIdx.x;
    double a = 0.0, b = 0.0, c = 0.0;
    #pragma unroll
    for (int bk = lane; bk < NBLK; bk += 64) {
        a += partial[4 * bk + 0];
        b += partial[4 * bk + 1];
        c += partial[4 * bk + 2];
    }
    #pragma unroll
    for (int off = 32; off > 0; off >>= 1) {
        a += __shfl_down(a, off);
        b += __shfl_down(b, off);
        c += __shfl_down(c, off);
    }
    if (lane == 0) {
        out[0] = (float)(a / (b + 1e-16));  // loss
        out[1] = (float)(b / (c + 1e-16));  // fraction_positive
    }
}

extern "C" void kernel_launch(void* const* d_in, const int* in_sizes, int n_in,
                              void* d_out, int out_size, void* d_ws, size_t ws_size,
                              hipStream_t stream) {
    const float* emb   = (const float*)d_in[0];   // [512,128] f32
    const int*   lab   = (const int*)d_in[1];     // [512] i32
    float*       out   = (float*)d_out;           // [2] f32: loss, fraction_positive
    double*      parts = (double*)d_ws;           // 4*NBLK doubles = 8 KB

    triplet_main_k<<<NBLK, 512, 0, stream>>>(emb, lab, parts);
    triplet_final_k<<<1, 64, 0, stream>>>(parts, out);
}